// Round 13
// baseline (57.345 us; speedup 1.0000x reference)
//
#include <hip/hip_runtime.h>

// NEmbedding: out[b,f,e] = relu( x*P[f,e] + R[f,e] + c * W[f,k,e] ),
// c = (hi_k - x)/(hi_k - lo_k),  P = sum_n g_n W_n,  R = bias - sum_n lo_n g_n W_n,
// k = largest n with bins[f,n] <= x (0 if none); hi of last bin = -1.0.
//
// R1-R9: batching (106->64); store-flavor/vmcnt/barrier/gather/latency dead.
// R10: fused single kernel (56.6). R11/R12: bf16 sW + bpermute transpose,
//      4 blocks/CU: NEUTRAL (56.4) -> occupancy/LDS-serialization dead.
// R13: write-contiguity test (last untested axis). FSL 8 -> 16: each out-row
//      written as 2KB contiguous (two adjacent dense 1KB wave-stores) instead
//      of 1KB islands; DRAM page-activation visits per row halve. Op counts
//      per byte unchanged (8 stores, ~44 DS/wave-iter). LDS 77.9KB -> 2
//      blocks/CU (R12 proved occupancy irrelevant). slice = blockIdx&3 keeps
//      exact XCD affinity (XCD k serves slice k&3).

#define FDIM 64
#define NB   64
#define EDIM 32
#define FSL  16     // features per slice
#define NRPB 128    // rows per block
#define ITERS (NRPB / 16)   // 16 rows per block-iter (4 waves x 4 rows)
#define SWSTR 34    // bf16 per n-row = 17 dwords (odd -> bank spread)

typedef __attribute__((ext_vector_type(4))) float f32x4;

static __device__ __forceinline__ unsigned bf16rne(float f) {
    unsigned u = __float_as_uint(f);
    return (u + 0x7FFFu + ((u >> 16) & 1u)) >> 16;
}

__global__ __launch_bounds__(256) void nemb_fused(
    const float* __restrict__ x, const float* __restrict__ bins,
    const float* __restrict__ W, const float* __restrict__ bias,
    float* __restrict__ out)
{
    __shared__ unsigned short sW16[FSL * NB * SWSTR];  // 69.6 KB bf16
    __shared__ float sBins[FSL * 65];                  // 65th = -1.0 sentinel
    __shared__ float sP[FSL * EDIM];
    __shared__ float sR[FSL * EDIM];

    const int t     = threadIdx.x;
    const int slice = blockIdx.x & 3;         // XCD k -> slice k&3 (affine)
    const int chunk = blockIdx.x >> 2;
    const int f0    = slice * FSL;

    const int w   = t >> 6;
    const int l   = t & 63;
    const int rs  = l >> 4;                   // search: row-in-4
    const int fs  = l & 15;                   // search: f-in-slice
    const int ftA = l >> 3;                   // store: f-half A (0..7)
    const int ftB = ftA + 8;                  // store: f-half B (8..15)
    const int e0  = (l & 7) * 4;              // store: e-quad

    const long r00 = (long)chunk * NRPB;

    // early independent loads (hidden under staging)
    float x_cur  = x[(r00 + w * 4 + rs) * FDIM + f0 + fs];
    float biasv0 = bias[(f0 + (t >> 5)) * EDIM + (t & 31)];
    float biasv1 = bias[(f0 + 8 + (t >> 5)) * EDIM + (t & 31)];

    // ---- stage W slice (128 KB fp32 -> 69.6 KB bf16) ----
    const float* Wg = W + (size_t)f0 * NB * EDIM;
    unsigned* sWd = reinterpret_cast<unsigned*>(sW16);
    #pragma unroll
    for (int i = 0; i < 32; ++i) {
        int qi = i * 256 + t;                 // f32x4 index within slice
        f32x4 v = reinterpret_cast<const f32x4*>(Wg)[qi];
        int gi = qi * 4;
        int fl = gi >> 11;                    // 0..15
        int n  = (gi >> 5) & 63;
        int ee = gi & 31;                     // multiple of 4
        unsigned u0 = bf16rne(v.x) | (bf16rne(v.y) << 16);
        unsigned u1 = bf16rne(v.z) | (bf16rne(v.w) << 16);
        int d0 = 17 * (fl * 64 + n) + (ee >> 1);
        sWd[d0]     = u0;
        sWd[d0 + 1] = u1;
    }
    // ---- stage bins slice (1024 floats) + sentinels ----
    {
        f32x4 v = reinterpret_cast<const f32x4*>(bins + (size_t)f0 * NB)[t];
        int gi = t * 4;
        int fl = gi >> 6, n = gi & 63;
        float* d = &sBins[fl * 65 + n];
        d[0] = v.x; d[1] = v.y; d[2] = v.z; d[3] = v.w;
    }
    if (t < FSL) sBins[t * 65 + 64] = -1.0f;
    __syncthreads();

    // ---- per-slice P/R from sBins (rcp) + bf16 sW; 2 passes of 8 f ----
    #pragma unroll
    for (int p = 0; p < 2; ++p) {
        const int fl = (t >> 5) + p * 8;
        const int e  = t & 31;
        float pp = 0.0f, qq = 0.0f;
        #pragma unroll
        for (int n = 0; n < NB; ++n) {
            float lo = sBins[fl * 65 + n];
            float hi = sBins[fl * 65 + n + 1];
            float gv = __builtin_amdgcn_rcpf(hi - lo);
            float wv = __uint_as_float(
                (unsigned)sW16[(fl * 64 + n) * SWSTR + e] << 16);
            pp = fmaf(gv, wv, pp);
            qq = fmaf(lo * gv, wv, qq);
        }
        sP[fl * EDIM + e] = pp;
        sR[fl * EDIM + e] = (p ? biasv1 : biasv0) - qq;
    }
    __syncthreads();

    // hoisted P/R fragments (fixed per lane, both f-halves)
    const f32x4 PvA = *reinterpret_cast<const f32x4*>(&sP[ftA * EDIM + e0]);
    const f32x4 RvA = *reinterpret_cast<const f32x4*>(&sR[ftA * EDIM + e0]);
    const f32x4 PvB = *reinterpret_cast<const f32x4*>(&sP[ftB * EDIM + e0]);
    const f32x4 RvB = *reinterpret_cast<const f32x4*>(&sR[ftB * EDIM + e0]);

    const float* bl = &sBins[fs * 65];
    const int aA0 = ftA * 4;                  // bpermute byte addr, +64*r
    const int aB0 = ftB * 4;

    #pragma unroll 2
    for (int it = 0; it < ITERS; ++it) {
        const long rb = r00 + it * 16 + w * 4;

        float xv = x_cur;
        if (it + 1 < ITERS)                   // prefetch next iteration's x
            x_cur = x[(rb + 16 + rs) * FDIM + f0 + fs];

        // ---- 8-ary counting search (lane owns row rb+rs, feature f0+fs) ----
        int k = 0;
        k += (bl[ 8] <= xv) ? 8 : 0;
        k += (bl[16] <= xv) ? 8 : 0;
        k += (bl[24] <= xv) ? 8 : 0;
        k += (bl[32] <= xv) ? 8 : 0;
        k += (bl[40] <= xv) ? 8 : 0;
        k += (bl[48] <= xv) ? 8 : 0;
        k += (bl[56] <= xv) ? 8 : 0;
        {
            const float* b2 = bl + k;
            int inner = 0;
            inner += (b2[1] <= xv) ? 1 : 0;
            inner += (b2[2] <= xv) ? 1 : 0;
            inner += (b2[3] <= xv) ? 1 : 0;
            inner += (b2[4] <= xv) ? 1 : 0;
            inner += (b2[5] <= xv) ? 1 : 0;
            inner += (b2[6] <= xv) ? 1 : 0;
            inner += (b2[7] <= xv) ? 1 : 0;
            k += inner;
        }
        float lo = bl[k];
        float hi = bl[k + 1];                 // k=63 -> sentinel -1.0
        float cv = (hi - xv) * __builtin_amdgcn_rcpf(hi - lo);

        // ---- transpose via ds_bpermute; 4 rows x 2KB contiguous stores ----
        #pragma unroll
        for (int r = 0; r < 4; ++r) {
            const int aA = aA0 + r * 64;      // src lane (r*16+ftA)*4
            const int aB = aB0 + r * 64;
            float xrA = __uint_as_float((unsigned)
                __builtin_amdgcn_ds_bpermute(aA, (int)__float_as_uint(xv)));
            float crA = __uint_as_float((unsigned)
                __builtin_amdgcn_ds_bpermute(aA, (int)__float_as_uint(cv)));
            int   krA = __builtin_amdgcn_ds_bpermute(aA, k);
            float xrB = __uint_as_float((unsigned)
                __builtin_amdgcn_ds_bpermute(aB, (int)__float_as_uint(xv)));
            float crB = __uint_as_float((unsigned)
                __builtin_amdgcn_ds_bpermute(aB, (int)__float_as_uint(cv)));
            int   krB = __builtin_amdgcn_ds_bpermute(aB, k);

            int dA = 17 * (ftA * 64 + krA) + ((l & 7) << 1);
            int dB = 17 * (ftB * 64 + krB) + ((l & 7) << 1);
            unsigned a0 = sWd[dA], a1 = sWd[dA + 1];
            unsigned b0 = sWd[dB], b1 = sWd[dB + 1];
            f32x4 WvA, WvB;
            WvA.x = __uint_as_float(a0 << 16);
            WvA.y = __uint_as_float(a0 & 0xFFFF0000u);
            WvA.z = __uint_as_float(a1 << 16);
            WvA.w = __uint_as_float(a1 & 0xFFFF0000u);
            WvB.x = __uint_as_float(b0 << 16);
            WvB.y = __uint_as_float(b0 & 0xFFFF0000u);
            WvB.z = __uint_as_float(b1 << 16);
            WvB.w = __uint_as_float(b1 & 0xFFFF0000u);

            f32x4 oA, oB;
            oA.x = fmaxf(fmaf(crA, WvA.x, fmaf(xrA, PvA.x, RvA.x)), 0.0f);
            oA.y = fmaxf(fmaf(crA, WvA.y, fmaf(xrA, PvA.y, RvA.y)), 0.0f);
            oA.z = fmaxf(fmaf(crA, WvA.z, fmaf(xrA, PvA.z, RvA.z)), 0.0f);
            oA.w = fmaxf(fmaf(crA, WvA.w, fmaf(xrA, PvA.w, RvA.w)), 0.0f);
            oB.x = fmaxf(fmaf(crB, WvB.x, fmaf(xrB, PvB.x, RvB.x)), 0.0f);
            oB.y = fmaxf(fmaf(crB, WvB.y, fmaf(xrB, PvB.y, RvB.y)), 0.0f);
            oB.z = fmaxf(fmaf(crB, WvB.z, fmaf(xrB, PvB.z, RvB.z)), 0.0f);
            oB.w = fmaxf(fmaf(crB, WvB.w, fmaf(xrB, PvB.w, RvB.w)), 0.0f);

            float* base = out + (rb + r) * (FDIM * EDIM) + f0 * EDIM;
            *reinterpret_cast<f32x4*>(base + ftA * EDIM + e0) = oA;  // 1KB dense
            *reinterpret_cast<f32x4*>(base + ftB * EDIM + e0) = oB;  // adjacent 1KB
        }
    }
}

extern "C" void kernel_launch(void* const* d_in, const int* in_sizes, int n_in,
                              void* d_out, int out_size, void* d_ws, size_t ws_size,
                              hipStream_t stream) {
    const float* x    = (const float*)d_in[0];   // (B, F)
    const float* bins = (const float*)d_in[1];   // (F, NB) sorted rows
    const float* W    = (const float*)d_in[2];   // (F, NB, E)
    const float* bias = (const float*)d_in[3];   // (F, E)
    float* out = (float*)d_out;

    const int B = in_sizes[0] / FDIM;            // 32768
    const int nchunks = B / NRPB;                // 256

    nemb_fused<<<nchunks * 4, 256, 0, stream>>>(x, bins, W, bias, out);
}

// Round 14
// 52.048 us; speedup vs baseline: 1.1018x; 1.1018x over previous
//
#include <hip/hip_runtime.h>

// NEmbedding: out[b,f,e] = relu( x*P[f,e] + R[f,e] + c * W[f,k,e] ),
// c = (hi_k - x)/(hi_k - lo_k),  P = sum_n g_n W_n,  R = bias - sum_n lo_n g_n W_n,
// k = largest n with bins[f,n] <= x (0 if none); hi of last bin = -1.0.
//
// R1-R13 summary: batching (106->64); fusion+slicing (->56.4 best, R12);
// dead theories: store flavor, within-iter vmcnt, barriers, W-gather, in-loop
// LDS latency, occupancy (2 vs 4 blk/CU identical), DS-op count (-30%
// identical), write contiguity (1KB vs 2KB islands identical).
// R14: the ONE untested vmcnt mechanism: R12's loop issues an x prefetch
//      (load) then 8 stores per iter; vmcnt retires in order, so consuming
//      x_cur forces vmcnt<=8 -> drains all older stores -> each wave is
//      re-gated every iteration on store-ack latency from the congested L2
//      write queue. Fix: preload all ITERS=8 x values into registers before
//      staging (full unroll, static indexing). The main loop then has ZERO
//      global loads -> no vmcnt waits at all -> store stream free-runs like
//      fillBufferAligned's (6.9 TB/s with no loop loads).

#define FDIM 64
#define NB   64
#define EDIM 32
#define FSL  8      // features per slice
#define NRPB 256    // rows per block
#define ITERS (NRPB / 32)
#define SWSTR 34    // bf16 per n-row = 17 dwords (odd -> bank spread)

typedef __attribute__((ext_vector_type(4))) float f32x4;

static __device__ __forceinline__ unsigned bf16rne(float f) {
    unsigned u = __float_as_uint(f);
    return (u + 0x7FFFu + ((u >> 16) & 1u)) >> 16;
}

__global__ __launch_bounds__(256) void nemb_fused(
    const float* __restrict__ x, const float* __restrict__ bins,
    const float* __restrict__ W, const float* __restrict__ bias,
    float* __restrict__ out)
{
    __shared__ unsigned short sW16[FSL * NB * SWSTR];  // 34.0 KB bf16
    __shared__ float sBins[FSL * 65];                  // 65th = -1.0 sentinel
    __shared__ float sP[FSL * EDIM];
    __shared__ float sR[FSL * EDIM];

    const int t     = threadIdx.x;
    const int slice = blockIdx.x & 7;         // XCD-affine under %8 dispatch
    const int chunk = blockIdx.x >> 3;
    const int f0    = slice * FSL;

    const int w  = t >> 6;
    const int l  = t & 63;
    const int rs = l >> 3;                    // search: row-in-8
    const int fs = l & 7;                     // search: f-in-slice
    const int ft = l >> 3;                    // store: f-in-slice
    const int e0 = (l & 7) * 4;               // store: e-quad

    const long r00 = (long)chunk * NRPB;

    // ---- preload ALL x values for this block's iterations (R14) ----
    // Issued before staging; independent of LDS. Removes every global load
    // from the main loop -> no vmcnt waits gate the store stream.
    float xpre[ITERS];
    #pragma unroll
    for (int it = 0; it < ITERS; ++it)
        xpre[it] = x[(r00 + it * 32 + w * 8 + rs) * FDIM + f0 + fs];

    float bias_v = bias[(f0 + (t >> 5)) * EDIM + (t & 31)];

    // ---- stage W slice as bf16 into LDS ----
    const float* Wg = W + (size_t)f0 * NB * EDIM;
    unsigned* sWd = reinterpret_cast<unsigned*>(sW16);
    #pragma unroll
    for (int i = 0; i < 16; ++i) {
        int qi = i * 256 + t;                 // f32x4 index within slice
        f32x4 v = reinterpret_cast<const f32x4*>(Wg)[qi];
        int gi = qi * 4;
        int fl = gi >> 11;                    // 0..7
        int n  = (gi >> 5) & 63;
        int ee = gi & 31;                     // multiple of 4
        unsigned u0 = bf16rne(v.x) | (bf16rne(v.y) << 16);
        unsigned u1 = bf16rne(v.z) | (bf16rne(v.w) << 16);
        int d0 = 17 * (fl * 64 + n) + (ee >> 1);
        sWd[d0]     = u0;
        sWd[d0 + 1] = u1;
    }
    // ---- stage bins slice + sentinels ----
    if (t < 128) {
        f32x4 v = reinterpret_cast<const f32x4*>(bins + (size_t)f0 * NB)[t];
        int gi = t * 4;
        int fl = gi >> 6, n = gi & 63;
        float* d = &sBins[fl * 65 + n];
        d[0] = v.x; d[1] = v.y; d[2] = v.z; d[3] = v.w;
    }
    if (t < FSL) sBins[t * 65 + 64] = -1.0f;
    __syncthreads();

    // ---- per-slice P/R from sBins (rcp) + bf16 sW ----
    {
        const int fl = t >> 5;
        const int e  = t & 31;
        float p = 0.0f, q = 0.0f;
        #pragma unroll
        for (int n = 0; n < NB; ++n) {
            float lo = sBins[fl * 65 + n];
            float hi = sBins[fl * 65 + n + 1];
            float gv = __builtin_amdgcn_rcpf(hi - lo);
            float wv = __uint_as_float((unsigned)sW16[(fl * 64 + n) * SWSTR + e] << 16);
            p = fmaf(gv, wv, p);
            q = fmaf(lo * gv, wv, q);
        }
        sP[fl * EDIM + e] = p;
        sR[fl * EDIM + e] = bias_v - q;
    }
    __syncthreads();

    // hoisted P/R fragments (fixed per lane)
    const f32x4 Pv = *reinterpret_cast<const f32x4*>(&sP[ft * EDIM + e0]);
    const f32x4 Rv = *reinterpret_cast<const f32x4*>(&sR[ft * EDIM + e0]);

    const float* bl = &sBins[fs * 65];
    const int bp_base = (l >> 3) * 4;         // bpermute byte addr component

    #pragma unroll
    for (int it = 0; it < ITERS; ++it) {      // full unroll: xpre static-indexed
        const long rb = r00 + it * 32 + w * 8;
        float xv = xpre[it];

        // ---- 8-ary counting search: 3 dependent LDS rounds ----
        int k = 0;
        k += (bl[ 8] <= xv) ? 8 : 0;
        k += (bl[16] <= xv) ? 8 : 0;
        k += (bl[24] <= xv) ? 8 : 0;
        k += (bl[32] <= xv) ? 8 : 0;
        k += (bl[40] <= xv) ? 8 : 0;
        k += (bl[48] <= xv) ? 8 : 0;
        k += (bl[56] <= xv) ? 8 : 0;
        {
            const float* b2 = bl + k;
            int inner = 0;
            inner += (b2[1] <= xv) ? 1 : 0;
            inner += (b2[2] <= xv) ? 1 : 0;
            inner += (b2[3] <= xv) ? 1 : 0;
            inner += (b2[4] <= xv) ? 1 : 0;
            inner += (b2[5] <= xv) ? 1 : 0;
            inner += (b2[6] <= xv) ? 1 : 0;
            inner += (b2[7] <= xv) ? 1 : 0;
            k += inner;
        }
        float lo = bl[k];
        float hi = bl[k + 1];                 // k=63 -> sentinel -1.0
        float cv = (hi - xv) * __builtin_amdgcn_rcpf(hi - lo);

        // ---- transpose via ds_bpermute (src = (l>>3) + r*8), store 8 rows ----
        #pragma unroll
        for (int r = 0; r < 8; ++r) {
            const int a = bp_base + r * 32;   // src_lane*4
            float xr = __uint_as_float((unsigned)
                __builtin_amdgcn_ds_bpermute(a, (int)__float_as_uint(xv)));
            float cr = __uint_as_float((unsigned)
                __builtin_amdgcn_ds_bpermute(a, (int)__float_as_uint(cv)));
            int   kr = __builtin_amdgcn_ds_bpermute(a, k);

            int d0 = 17 * (ft * 64 + kr) + ((l & 7) << 1);
            unsigned u0 = sWd[d0];
            unsigned u1 = sWd[d0 + 1];
            f32x4 Wv;
            Wv.x = __uint_as_float(u0 << 16);
            Wv.y = __uint_as_float(u0 & 0xFFFF0000u);
            Wv.z = __uint_as_float(u1 << 16);
            Wv.w = __uint_as_float(u1 & 0xFFFF0000u);

            f32x4 o;
            o.x = fmaxf(fmaf(cr, Wv.x, fmaf(xr, Pv.x, Rv.x)), 0.0f);
            o.y = fmaxf(fmaf(cr, Wv.y, fmaf(xr, Pv.y, Rv.y)), 0.0f);
            o.z = fmaxf(fmaf(cr, Wv.z, fmaf(xr, Pv.z, Rv.z)), 0.0f);
            o.w = fmaxf(fmaf(cr, Wv.w, fmaf(xr, Pv.w, Rv.w)), 0.0f);
            *reinterpret_cast<f32x4*>(
                out + (rb + r) * (FDIM * EDIM) + (f0 + ft) * EDIM + e0) = o;
        }
    }
}

extern "C" void kernel_launch(void* const* d_in, const int* in_sizes, int n_in,
                              void* d_out, int out_size, void* d_ws, size_t ws_size,
                              hipStream_t stream) {
    const float* x    = (const float*)d_in[0];   // (B, F)
    const float* bins = (const float*)d_in[1];   // (F, NB) sorted rows
    const float* W    = (const float*)d_in[2];   // (F, NB, E)
    const float* bias = (const float*)d_in[3];   // (F, E)
    float* out = (float*)d_out;

    const int B = in_sizes[0] / FDIM;            // 32768
    const int nchunks = B / NRPB;                // 128

    nemb_fused<<<nchunks * 8, 256, 0, stream>>>(x, bins, W, bias, out);
}

// Round 15
// 51.659 us; speedup vs baseline: 1.1101x; 1.0075x over previous
//
#include <hip/hip_runtime.h>

// NEmbedding: out[b,f,e] = relu( x*P[f,e] + R[f,e] + c * W[f,k,e] ),
// c = (hi_k - x)/(hi_k - lo_k),  P = sum_n g_n W_n,  R = bias - sum_n lo_n g_n W_n,
// k = largest n with bins[f,n] <= x (0 if none); hi of last bin = -1.0.
//
// R1-R13: batching, fusion, slicing (56.4); many dead theories (see log).
// R14: zero global loads in main loop -> no vmcnt wait gates the store
//      stream -> 52.0 (-4.4, matched prediction). Mechanism confirmed.
// R15: extend R14's mechanism: (a) hoist ALL searches into the prologue,
//      interleaved under the W-staging global-load shadow (searches need only
//      sBins, staged first behind an early barrier; staging loads in flight
//      are not drained by consuming older xpre loads - vmcnt is in-order);
//      (b) pack k into c's low 6 mantissa bits (rel err 2^-17, |c*W|<~2e5 ->
//      abs err ~2 << 3625) -> 2 bpermutes/row not 3. Main loop: 32 DS ops
//      (16 bpermute + 16 b32 W-reads) + 8 stores, nothing else.

#define FDIM 64
#define NB   64
#define EDIM 32
#define FSL  8      // features per slice
#define NRPB 256    // rows per block
#define ITERS (NRPB / 32)
#define SWSTR 34    // bf16 per n-row = 17 dwords (odd -> bank spread)

typedef __attribute__((ext_vector_type(4))) float f32x4;

static __device__ __forceinline__ unsigned bf16rne(float f) {
    unsigned u = __float_as_uint(f);
    return (u + 0x7FFFu + ((u >> 16) & 1u)) >> 16;
}

__global__ __launch_bounds__(256) void nemb_fused(
    const float* __restrict__ x, const float* __restrict__ bins,
    const float* __restrict__ W, const float* __restrict__ bias,
    float* __restrict__ out)
{
    __shared__ unsigned short sW16[FSL * NB * SWSTR];  // 34.0 KB bf16
    __shared__ float sBins[FSL * 65];                  // 65th = -1.0 sentinel
    __shared__ float sP[FSL * EDIM];
    __shared__ float sR[FSL * EDIM];

    const int t     = threadIdx.x;
    const int slice = blockIdx.x & 7;         // XCD-affine under %8 dispatch
    const int chunk = blockIdx.x >> 3;
    const int f0    = slice * FSL;

    const int w  = t >> 6;
    const int l  = t & 63;
    const int rs = l >> 3;                    // search: row-in-8
    const int fs = l & 7;                     // search: f-in-slice
    const int ft = l >> 3;                    // store: f-in-slice
    const int e0 = (l & 7) * 4;               // store: e-quad

    const long r00 = (long)chunk * NRPB;

    // ---- stage sBins FIRST (searches depend only on it) ----
    if (t < 128) {
        f32x4 v = reinterpret_cast<const f32x4*>(bins + (size_t)f0 * NB)[t];
        int gi = t * 4;
        int fl = gi >> 6, n = gi & 63;
        float* d = &sBins[fl * 65 + n];
        d[0] = v.x; d[1] = v.y; d[2] = v.z; d[3] = v.w;
    }
    if (t < FSL) sBins[t * 65 + 64] = -1.0f;
    __syncthreads();                          // barrier 1: sBins ready

    // ---- issue xpre (consumed by searches) then staging half A ----
    float xpre[ITERS];
    #pragma unroll
    for (int it = 0; it < ITERS; ++it)
        xpre[it] = x[(r00 + it * 32 + w * 8 + rs) * FDIM + f0 + fs];
    float bias_v = bias[(f0 + (t >> 5)) * EDIM + (t & 31)];

    const float* Wg = W + (size_t)f0 * NB * EDIM;
    unsigned* sWd = reinterpret_cast<unsigned*>(sW16);

    f32x4 vstg[8];
    #pragma unroll
    for (int i = 0; i < 8; ++i)               // half A: fl 0..3
        vstg[i] = reinterpret_cast<const f32x4*>(Wg)[i * 256 + t];

    // ---- searches (pure sBins/VALU) run while half-A loads are in flight ----
    const float* bl = &sBins[fs * 65];
    unsigned pk[ITERS];
    #pragma unroll
    for (int it = 0; it < ITERS; ++it) {
        float xv = xpre[it];
        int k = 0;
        k += (bl[ 8] <= xv) ? 8 : 0;
        k += (bl[16] <= xv) ? 8 : 0;
        k += (bl[24] <= xv) ? 8 : 0;
        k += (bl[32] <= xv) ? 8 : 0;
        k += (bl[40] <= xv) ? 8 : 0;
        k += (bl[48] <= xv) ? 8 : 0;
        k += (bl[56] <= xv) ? 8 : 0;
        const float* b2 = bl + k;
        int inner = 0;
        inner += (b2[1] <= xv) ? 1 : 0;
        inner += (b2[2] <= xv) ? 1 : 0;
        inner += (b2[3] <= xv) ? 1 : 0;
        inner += (b2[4] <= xv) ? 1 : 0;
        inner += (b2[5] <= xv) ? 1 : 0;
        inner += (b2[6] <= xv) ? 1 : 0;
        inner += (b2[7] <= xv) ? 1 : 0;
        k += inner;
        float lo = bl[k];
        float hi = bl[k + 1];                 // k=63 -> sentinel -1.0
        float cv = (hi - xv) * __builtin_amdgcn_rcpf(hi - lo);
        pk[it] = (__float_as_uint(cv) & ~63u) | (unsigned)k;  // k in mantissa lo bits
    }

    // ---- write half A, issue+write half B ----
    #pragma unroll
    for (int i = 0; i < 8; ++i) {
        int gi = (i * 256 + t) * 4;
        int fl = gi >> 11, n = (gi >> 5) & 63, ee = gi & 31;
        unsigned u0 = bf16rne(vstg[i].x) | (bf16rne(vstg[i].y) << 16);
        unsigned u1 = bf16rne(vstg[i].z) | (bf16rne(vstg[i].w) << 16);
        int d0 = 17 * (fl * 64 + n) + (ee >> 1);
        sWd[d0] = u0; sWd[d0 + 1] = u1;
    }
    #pragma unroll
    for (int i = 8; i < 16; ++i)              // half B: fl 4..7
        vstg[i - 8] = reinterpret_cast<const f32x4*>(Wg)[i * 256 + t];
    #pragma unroll
    for (int i = 8; i < 16; ++i) {
        int gi = (i * 256 + t) * 4;
        int fl = gi >> 11, n = (gi >> 5) & 63, ee = gi & 31;
        unsigned u0 = bf16rne(vstg[i - 8].x) | (bf16rne(vstg[i - 8].y) << 16);
        unsigned u1 = bf16rne(vstg[i - 8].z) | (bf16rne(vstg[i - 8].w) << 16);
        int d0 = 17 * (fl * 64 + n) + (ee >> 1);
        sWd[d0] = u0; sWd[d0 + 1] = u1;
    }
    __syncthreads();                          // barrier 2: sW ready

    // ---- per-slice P/R from sBins (rcp) + bf16 sW ----
    {
        const int fl = t >> 5;
        const int e  = t & 31;
        float p = 0.0f, q = 0.0f;
        #pragma unroll
        for (int n = 0; n < NB; ++n) {
            float lo = sBins[fl * 65 + n];
            float hi = sBins[fl * 65 + n + 1];
            float gv = __builtin_amdgcn_rcpf(hi - lo);
            float wv = __uint_as_float((unsigned)sW16[(fl * 64 + n) * SWSTR + e] << 16);
            p = fmaf(gv, wv, p);
            q = fmaf(lo * gv, wv, q);
        }
        sP[fl * EDIM + e] = p;
        sR[fl * EDIM + e] = bias_v - q;
    }
    __syncthreads();                          // barrier 3: sP/sR ready

    const f32x4 Pv = *reinterpret_cast<const f32x4*>(&sP[ft * EDIM + e0]);
    const f32x4 Rv = *reinterpret_cast<const f32x4*>(&sR[ft * EDIM + e0]);
    const int bp_base = (l >> 3) * 4;         // bpermute byte addr component

    // ---- main loop: ZERO global loads, ZERO searches — just emit ----
    #pragma unroll
    for (int it = 0; it < ITERS; ++it) {
        const long rb = r00 + it * 32 + w * 8;
        const float    xv  = xpre[it];
        const unsigned pkv = pk[it];

        #pragma unroll
        for (int r = 0; r < 8; ++r) {
            const int a = bp_base + r * 32;   // src_lane*4
            float xr = __uint_as_float((unsigned)
                __builtin_amdgcn_ds_bpermute(a, (int)__float_as_uint(xv)));
            unsigned pr = (unsigned)__builtin_amdgcn_ds_bpermute(a, (int)pkv);
            int   kr = (int)(pr & 63u);
            float cr = __uint_as_float(pr & ~63u);

            int d0 = 17 * (ft * 64 + kr) + ((l & 7) << 1);
            unsigned u0 = sWd[d0];
            unsigned u1 = sWd[d0 + 1];
            f32x4 Wv;
            Wv.x = __uint_as_float(u0 << 16);
            Wv.y = __uint_as_float(u0 & 0xFFFF0000u);
            Wv.z = __uint_as_float(u1 << 16);
            Wv.w = __uint_as_float(u1 & 0xFFFF0000u);

            f32x4 o;
            o.x = fmaxf(fmaf(cr, Wv.x, fmaf(xr, Pv.x, Rv.x)), 0.0f);
            o.y = fmaxf(fmaf(cr, Wv.y, fmaf(xr, Pv.y, Rv.y)), 0.0f);
            o.z = fmaxf(fmaf(cr, Wv.z, fmaf(xr, Pv.z, Rv.z)), 0.0f);
            o.w = fmaxf(fmaf(cr, Wv.w, fmaf(xr, Pv.w, Rv.w)), 0.0f);
            *reinterpret_cast<f32x4*>(
                out + (rb + r) * (FDIM * EDIM) + (f0 + ft) * EDIM + e0) = o;
        }
    }
}

extern "C" void kernel_launch(void* const* d_in, const int* in_sizes, int n_in,
                              void* d_out, int out_size, void* d_ws, size_t ws_size,
                              hipStream_t stream) {
    const float* x    = (const float*)d_in[0];   // (B, F)
    const float* bins = (const float*)d_in[1];   // (F, NB) sorted rows
    const float* W    = (const float*)d_in[2];   // (F, NB, E)
    const float* bias = (const float*)d_in[3];   // (F, E)
    float* out = (float*)d_out;

    const int B = in_sizes[0] / FDIM;            // 32768
    const int nchunks = B / NRPB;                // 128

    nemb_fused<<<nchunks * 8, 256, 0, stream>>>(x, bins, W, bias, out);
}